// Round 13
// baseline (407.329 us; speedup 1.0000x reference)
//
#include <hip/hip_runtime.h>
#include <math.h>

#define NN 50000
#define FEAT 256
#define HID 128
#define NA 32
#define NP 4
#define TM 64
#define NBLK 782            // ceil(50000/64)
#define LDA 132
#define EPSS 1e-12f
#define LN_EPS 1e-5f

typedef unsigned short u16;
typedef __attribute__((ext_vector_type(8))) short bf16x8;
typedef __attribute__((ext_vector_type(4))) float f32x4;

// ---- workspace layout (float offsets) ----
#define ADJ_F   0           // adj fp32 (NN*NA)
#define RS_F    1600000
#define CS_F    1650000
#define AGG0_F  1650032
#define AGG1_F  1654128
#define HB_F    1658256     // hb[p][k][a] fp32 (16384); later reused for T (4096)
#define FLAG_F  1674640     // int flags[19] (pad 32)
#define F_END   1674672
// ---- u16 offsets ----
#define XC_U   (2 * F_END)            // 3349344
#define SUP_U  (XC_U + NN * HID)      // 9749344
#define PW_U   (SUP_U + NN * HID)     // 16149344
#define PW_TOT 165638
#define WS_NEED_BYTES ((size_t)(PW_U + PW_TOT) * 2ULL)
// The XC and SUP regions (25.6 MB contiguous) are permanently dead as named
// buffers (sup/t/xc never materialized). Scratch carved from them:
//   csPart: XC_U + 0      (NA*NBLK floats, 100 KB)
//   partb : XC_U + 128KB  (NBLK*4096 floats = 12.81 MB, spans into SUP)
// wc[p][a] (128 floats) aliases AGG1_F: written by k_pre, consumed by k_fattn;
// k_small hop-1 overwrites AGG1_F long after attention is done.

// ---- packed bf16 weights; matrices stored TRANSPOSED [n][k] ----
#define PK_IMW1T  0         // 128x256
#define PK_IMW2T  32768     // 128x128
#define PK_MLW1T  49152     // 4 x (128x128)  (Wx^T only)
#define PK_ENCWT  114688    // 2 x (128x128)
#define PK_CLSW1T 147456    // 128x128
#define PK_IMB1   163840
#define PK_IMB2   163968
#define PK_MLW2   164096    // 4x128
#define PK_ENCB   164608    // 2x128
#define PK_LNG    164864
#define PK_LNB    164992
#define PK_CLSB1  165120
#define PK_PRELU  165248
#define PK_CLSW2  165376    // 128x2
#define PK_CLSB2  165632
#define PK_MLB2   165634
#define PK_TOTAL  165638

// ---- output layout (fp32 element offsets) ----
#define PRED_OFF 0
#define Z_OFF    100000
#define AV_OFF   6500000
#define AL_OFF   6504096
#define OUT_TOT  6504160

__device__ __constant__ int kNel[19] = {
    NN * FEAT, FEAT * HID, HID, HID * HID, HID, NA * HID,
    NP * 2 * HID * HID, NP * HID, NP * HID, NP, 2 * HID * HID, 2 * HID,
    HID, HID, HID * HID, HID, HID, HID * 2, 2};

// transposed-matrix convert segments (seg 0: K=256, 32 tiles; segs 1-8: K=128,
// 16 tiles each; 160 tiles total, 32x32 each)
__device__ __constant__ int tDst[9]  = {PK_IMW1T,PK_IMW2T,PK_MLW1T,PK_MLW1T+16384,
                                        PK_MLW1T+32768,PK_MLW1T+49152,PK_ENCWT,
                                        PK_ENCWT+16384,PK_CLSW1T};
__device__ __constant__ int tSrcT[9] = {1,3,6,6,6,6,10,10,14};
__device__ __constant__ int tBase[9] = {0,0,0,32768,65536,98304,0,16384,0};
// vector convert segments
#define VSEG_TOT 1798
__device__ __constant__ int vLen[11] = {128,128,512,256,128,128,128,128,256,2,4};
__device__ __constant__ int vDst[11] = {PK_IMB1,PK_IMB2,PK_MLW2,PK_ENCB,PK_LNG,PK_LNB,
                                        PK_CLSB1,PK_PRELU,PK_CLSW2,PK_CLSB2,PK_MLB2};
__device__ __constant__ int vSrcT[11]= {2,4,8,11,12,13,15,16,17,18,9};

struct P19 { const void* q[19]; };

__device__ __forceinline__ float b2f(u16 u) {
    union { float f; unsigned int i; } v; v.i = ((unsigned int)u) << 16; return v.f;
}
__device__ __forceinline__ u16 f2b(float f) {
    union { float f; unsigned int i; } v; v.f = f;
    unsigned int x = v.i;
    x += 0x7fffu + ((x >> 16) & 1u);   // RNE
    return (u16)(x >> 16);
}
// flag: 0 = bf16, 1 = fp32, 2 = all-zero
__device__ __forceinline__ float ldf(const void* p, size_t i, int fl) {
    if (fl == 1) return ((const float*)p)[i];
    if (fl == 0) return b2f(((const u16*)p)[i]);
    return 0.f;
}

// ---- per-tensor dtype detector (first min(N,8192) u16s only) ----
__global__ __launch_bounds__(256) void k_detect_all(P19 a, int* __restrict__ flags) {
    __shared__ int sHi[256], sE[256], sO[256];
    const int b = blockIdx.x;
    const u16* p = (const u16*)a.q[b];
    const int M = (kNel[b] < 8192) ? kNel[b] : 8192;
    int cHi = 0, cE = 0, cO = 0;
    for (int j = threadIdx.x; j < M; j += 256) {
        const u16 v = p[j];
        if (j & 1) cO += (v != 0);
        else { cE += (v != 0); cHi += (((v >> 7) & 0xFF) >= 200); }
    }
    sHi[threadIdx.x] = cHi; sE[threadIdx.x] = cE; sO[threadIdx.x] = cO;
    __syncthreads();
    for (int s = 128; s > 0; s >>= 1) {
        if (threadIdx.x < (unsigned)s) {
            sHi[threadIdx.x] += sHi[threadIdx.x + s];
            sE[threadIdx.x]  += sE[threadIdx.x + s];
            sO[threadIdx.x]  += sO[threadIdx.x + s];
        }
        __syncthreads();
    }
    if (threadIdx.x == 0) {
        int f;
        if (sE[0] == 0 && sO[0] == 0) f = 2;
        else if (sHi[0] >= 4 || sE[0] == 0) f = 1;
        else f = 0;
        flags[b] = f;
    }
}

// ---- pack weights: 32x32 LDS tile-transpose (coalesced src reads AND dst
// writes). pw[dst + n*K + k] = src[base + k*128 + n]. Block 160 = vector params.
__global__ __launch_bounds__(256) void k_convT(P19 a, const int* __restrict__ flags,
                                               u16* __restrict__ pw) {
    const int b = blockIdx.x;
    if (b == 160) {                      // vector params (old k_convV)
        for (int idx = threadIdx.x; idx < VSEG_TOT; idx += 256) {
            int off = idx, s = 0;
            while (off >= vLen[s]) { off -= vLen[s]; ++s; }
            const int si = vSrcT[s];
            pw[vDst[s] + off] = f2b(ldf(a.q[si], off, flags[si]));
        }
        return;
    }
    __shared__ float tle[32][33];
    int s, t;
    if (b < 32) { s = 0; t = b; }
    else        { s = 1 + (b - 32) / 16; t = (b - 32) % 16; }
    const int K = (s == 0) ? 256 : 128;
    const int tn = (t & 3) * 32, tk = (t >> 2) * 32;
    const int si = tSrcT[s], fl = flags[si];
    const int c0 = threadIdx.x & 31, q0 = threadIdx.x >> 5;
#pragma unroll
    for (int i = 0; i < 4; ++i) {
        const int kk = q0 + i * 8;
        tle[kk][c0] = ldf(a.q[si],
                          (size_t)tBase[s] + (size_t)(tk + kk) * 128 + tn + c0, fl);
    }
    __syncthreads();
#pragma unroll
    for (int i = 0; i < 4; ++i) {
        const int nn = q0 + i * 8;
        pw[tDst[s] + (size_t)(tn + nn) * K + tk + c0] = f2b(tle[c0][nn]);
    }
}

// ---- MFMA core: 64x128 tile, wave wv handles rows wv*16..+16, all 128 cols.
__device__ __forceinline__ void mfma_64x128(const u16* As, const u16* Bt,
                                            f32x4 acc[8], int lane, int rowBase) {
    const int lr = lane & 15, lq = lane >> 4;
#pragma unroll
    for (int kc = 0; kc < 4; ++kc) {
        bf16x8 a = *(const bf16x8*)(As + (rowBase + lr) * 136 + kc * 32 + lq * 8);
#pragma unroll
        for (int t = 0; t < 8; ++t) {
            bf16x8 b = *(const bf16x8*)(Bt + (t * 16 + lr) * 136 + kc * 32 + lq * 8);
            acc[t] = __builtin_amdgcn_mfma_f32_16x16x32_bf16(a, b, acc[t], 0, 0, 0);
        }
    }
}

// ---- Fused im MLP v2: h = relu(x@W1+b1)@W2+b2. x A-fragments in regs (fattn
// pattern); B staged in 64-row halves (Bt 64x136). LDS 34.8KB -> 4 blocks/CU.
__global__ __launch_bounds__(256) void k_gemm2(const void* __restrict__ A,
                                               const u16* __restrict__ pw,
                                               float* __restrict__ outh,
                                               const int* __restrict__ flags) {
    __shared__ __align__(16) u16 As[64 * 136];   // t tile (pass-2 A operand)
    __shared__ __align__(16) u16 Bt[64 * 136];   // B half staging
    const int fA = flags[0];
    const int tid = threadIdx.x;
    const int row0 = blockIdx.x * TM;
    const int lane = tid & 63, wv = tid >> 6, rowBase = wv * 16;
    const int lr = lane & 15, lq = lane >> 4;

    // x A-fragments (8 k-chunks of 32), fp32/bf16 -> bf16 regs
    bf16x8 ax[8];
    {
        const int gr = row0 + rowBase + lr;
#pragma unroll
        for (int kc = 0; kc < 8; ++kc) {
            bf16x8 t;
            if (gr < NN) {
                const size_t idx = (size_t)gr * FEAT + kc * 32 + lq * 8;
                if (fA == 1) {
                    const float* src = (const float*)A + idx;
                    float4 v0 = *(const float4*)src;
                    float4 v1 = *(const float4*)(src + 4);
                    t[0] = (short)f2b(v0.x); t[1] = (short)f2b(v0.y);
                    t[2] = (short)f2b(v0.z); t[3] = (short)f2b(v0.w);
                    t[4] = (short)f2b(v1.x); t[5] = (short)f2b(v1.y);
                    t[6] = (short)f2b(v1.z); t[7] = (short)f2b(v1.w);
                } else {
                    t = *(const bf16x8*)((const u16*)A + idx);
                }
            } else {
#pragma unroll
                for (int j = 0; j < 8; ++j) t[j] = 0;
            }
            ax[kc] = t;
        }
    }

    f32x4 acc[8];
    const f32x4 z4 = {0.f, 0.f, 0.f, 0.f};
#pragma unroll
    for (int t = 0; t < 8; ++t) acc[t] = z4;

    // pass 1: t = relu(x@W1+b1); 2 n-halves x 2 K-chunks, Bt64 staging
    for (int half = 0; half < 2; ++half) {
        for (int kc2 = 0; kc2 < 2; ++kc2) {
            __syncthreads();                 // prev Bt reads done
            for (int i = tid; i < 64 * 32; i += 256) {
                const int n = i >> 5, k4 = (i & 31) << 2;
                *(ushort4*)&Bt[n * 136 + k4] =
                    *(const ushort4*)(pw + PK_IMW1T +
                                      (size_t)(half * 64 + n) * FEAT + kc2 * 128 + k4);
            }
            __syncthreads();                 // Bt ready
#pragma unroll
            for (int kc = 0; kc < 4; ++kc)
#pragma unroll
                for (int tt = 0; tt < 4; ++tt) {
                    bf16x8 b = *(const bf16x8*)(Bt + (tt * 16 + lr) * 136 + kc * 32 + lq * 8);
                    acc[half * 4 + tt] = __builtin_amdgcn_mfma_f32_16x16x32_bf16(
                        ax[kc2 * 4 + kc], b, acc[half * 4 + tt], 0, 0, 0);
                }
        }
    }
    // t tile (relu + b1, bf16) scattered into As
#pragma unroll
    for (int t = 0; t < 8; ++t) {
        const int col = t * 16 + lr;
        const float bv = b2f(pw[PK_IMB1 + col]);
#pragma unroll
        for (int r = 0; r < 4; ++r)
            As[(rowBase + lq * 4 + r) * 136 + col] = f2b(fmaxf(acc[t][r] + bv, 0.f));
    }
    // pass 2: h = t@W2+b2; 2 n-halves, Bt64 staging; A-frags from As
    f32x4 acc2[8];
#pragma unroll
    for (int t = 0; t < 8; ++t) acc2[t] = z4;
    for (int half = 0; half < 2; ++half) {
        __syncthreads();                     // prev Bt reads done + As writes done
        for (int i = tid; i < 64 * 32; i += 256) {
            const int n = i >> 5, k4 = (i & 31) << 2;
            *(ushort4*)&Bt[n * 136 + k4] =
                *(const ushort4*)(pw + PK_IMW2T + (size_t)(half * 64 + n) * HID + k4);
        }
        __syncthreads();                     // Bt ready
#pragma unroll
        for (int kc = 0; kc < 4; ++kc) {
            bf16x8 a = *(const bf16x8*)(As + (rowBase + lr) * 136 + kc * 32 + lq * 8);
#pragma unroll
            for (int tt = 0; tt < 4; ++tt) {
                bf16x8 b = *(const bf16x8*)(Bt + (tt * 16 + lr) * 136 + kc * 32 + lq * 8);
                acc2[half * 4 + tt] = __builtin_amdgcn_mfma_f32_16x16x32_bf16(
                    a, b, acc2[half * 4 + tt], 0, 0, 0);
            }
        }
    }
#pragma unroll
    for (int t = 0; t < 8; ++t) {
        const int col = t * 16 + lr;
        const float bv = b2f(pw[PK_IMB2 + col]);
#pragma unroll
        for (int r = 0; r < 4; ++r) {
            const int g = row0 + rowBase + lq * 4 + r;
            if (g < NN) outh[(size_t)g * HID + col] = acc2[t][r] + bv;
        }
    }
}

// hb[p][k][a] = (anchors @ Wa[p] + ml_b1[p]) transposed; also reduces
// wc[p][a] = sum_k 0.5*w2[p][k]*hb[p][k][a] in-block (old k_wc fused).
__global__ __launch_bounds__(128) void k_pre(const void* __restrict__ anchors,
                                             const void* __restrict__ ml_w1,
                                             const void* __restrict__ ml_b1,
                                             const void* __restrict__ ml_w2,
                                             float* __restrict__ hb,
                                             float* __restrict__ wc,
                                             const int* __restrict__ flags) {
    __shared__ float sa[HID];
    __shared__ float red[128];
    const int fAn = flags[5], fW1 = flags[6], fB1 = flags[7], fW2 = flags[8];
    const int p = blockIdx.x >> 5, a = blockIdx.x & 31, k = threadIdx.x;
    sa[k] = ldf(anchors, a * HID + k, fAn);
    __syncthreads();
    float acc = ldf(ml_b1, p * HID + k, fB1);
    const size_t wbase = ((size_t)p * 2 * HID + HID) * HID + k;
#pragma unroll 4
    for (int j = 0; j < HID; ++j)
        acc += sa[j] * ldf(ml_w1, wbase + (size_t)j * HID, fW1);
    hb[p * (NA * HID) + k * NA + a] = acc;
    red[k] = 0.5f * ldf(ml_w2, p * HID + k, fW2) * acc;
    __syncthreads();
    for (int st = 64; st > 0; st >>= 1) {
        if (k < st) red[k] += red[k + st];
        __syncthreads();
    }
    if (k == 0) wc[p * NA + a] = red[0];
}

// anchor classifier + anchor_vec copy (fp32 outputs, raw inputs via flags)
__global__ __launch_bounds__(256) void k_anchor(const void* __restrict__ anchors,
                                                const void* __restrict__ cls_w1,
                                                const void* __restrict__ cls_b1,
                                                const void* __restrict__ prelu_a,
                                                const void* __restrict__ cls_w2,
                                                const void* __restrict__ cls_b2,
                                                float* __restrict__ out,
                                                const int* __restrict__ flags) {
    __shared__ float sa[2][HID];
    __shared__ float st1[2][HID];
    const int fAn = flags[5], fW1 = flags[14], fB1 = flags[15];
    const int fPa = flags[16], fW2 = flags[17], fB2 = flags[18];
    const int tid = threadIdx.x;
    const int a0 = blockIdx.x * 2;
    const int half = tid >> 7, k = tid & 127;
    sa[half][k] = ldf(anchors, (a0 + half) * HID + k, fAn);
    __syncthreads();
    float acc = ldf(cls_b1, k, fB1);
#pragma unroll 4
    for (int j = 0; j < HID; ++j) acc += sa[half][j] * ldf(cls_w1, j * HID + k, fW1);
    const float pa = ldf(prelu_a, k, fPa);
    st1[half][k] = acc > 0.f ? acc : pa * acc;
    __syncthreads();
    if (tid < 4) {
        const int aa = tid >> 1, c = tid & 1;
        float s = ldf(cls_b2, c, fB2);
        for (int j = 0; j < HID; ++j) s += st1[aa][j] * ldf(cls_w2, j * 2 + c, fW2);
        out[AL_OFF + (a0 + aa) * 2 + c] = s;
    }
    if (blockIdx.x == 0) {
        for (int i = tid; i < NA * HID; i += 256)
            out[AV_OFF + i] = ldf(anchors, i, fAn);
    }
}

// Fused attention v7: __launch_bounds__(256,4) raises the VGPR budget to 128
// (kernel is LDS-limited to 4 blocks/CU anyway), so hb can be loaded EARLY
// into regs (latency hidden under Wx staging + MFMA) without spilling.
// hop-0 aggT fused in epilogue. Writes adj, rowsum, csPart, part.
__global__ __launch_bounds__(256, 4) void k_fattn(const float* __restrict__ h,
                                               const u16* __restrict__ pw,
                                               const float* __restrict__ hb,
                                               const float* __restrict__ wc,
                                               float* __restrict__ adj,
                                               float* __restrict__ rowsum,
                                               float* __restrict__ csPart,
                                               float* __restrict__ part) {
    __shared__ __align__(16) u16 Bt[128 * 136];   // Wx^T -> {hx 0-63, hb(f32) 64-127}
    __shared__ float hws[HID];
    __shared__ float wcs[NA];
    __shared__ float swr[4][NA];
    float* hbf = (float*)&Bt[64 * 136];           // 4352 floats capacity, 4096 used
    const int tid = threadIdx.x;
    const int row0 = blockIdx.x * TM;
    const int lane = tid & 63, wv = tid >> 6, rowBase = wv * 16;
    const int lr = lane & 15, lq = lane >> 4;
    const int g = tid & 3, myrow = tid >> 2;        // 4 anchor-groups x 64 rows
    const int a0 = g * 8;

    // A-fragments (h tile, fp32->bf16) held in regs; identical for all 4 p's
    bf16x8 afr[4];
    {
        const int gr = row0 + rowBase + lr;
#pragma unroll
        for (int kc = 0; kc < 4; ++kc) {
            bf16x8 t;
            if (gr < NN) {
                const float* src = h + (size_t)gr * HID + kc * 32 + lq * 8;
                float4 v0 = *(const float4*)src;
                float4 v1 = *(const float4*)(src + 4);
                t[0] = (short)f2b(v0.x); t[1] = (short)f2b(v0.y);
                t[2] = (short)f2b(v0.z); t[3] = (short)f2b(v0.w);
                t[4] = (short)f2b(v1.x); t[5] = (short)f2b(v1.y);
                t[6] = (short)f2b(v1.z); t[7] = (short)f2b(v1.w);
            } else {
#pragma unroll
                for (int j = 0; j < 8; ++j) t[j] = 0;
            }
            afr[kc] = t;
        }
    }

    float adjacc[8];
#pragma unroll
    for (int j = 0; j < 8; ++j) adjacc[j] = 0.f;

    for (int p = 0; p < NP; ++p) {
        __syncthreads();                            // prev p's LDS reads done
        for (int i = tid; i < 128 * 32; i += 256) { // Wx^T -> Bt
            const int n = i >> 5, k4 = (i & 31) << 2;
            *(ushort4*)&Bt[n * 136 + k4] =
                *(const ushort4*)(pw + PK_MLW1T + p * 16384 + n * 128 + k4);
        }
        // early-issue hb loads: latency hides under staging-wait + MFMA
        float4 hbreg[4];
        {
            const float4* hbp4 = (const float4*)(hb + (size_t)p * (NA * HID));
#pragma unroll
            for (int j = 0; j < 4; ++j) hbreg[j] = hbp4[tid + j * 256];
        }
        if (tid < HID) hws[tid] = 0.5f * b2f(pw[PK_MLW2 + p * HID + tid]);
        if (tid < NA) wcs[tid] = wc[p * NA + tid];
        __syncthreads();                            // Bt/hws/wcs ready

        f32x4 acc[8];
        const f32x4 z4 = {0.f, 0.f, 0.f, 0.f};
#pragma unroll
        for (int t = 0; t < 8; ++t) acc[t] = z4;
#pragma unroll
        for (int kc = 0; kc < 4; ++kc)
#pragma unroll
            for (int t = 0; t < 8; ++t) {
                bf16x8 b = *(const bf16x8*)(Bt + (t * 16 + lr) * 136 + kc * 32 + lq * 8);
                acc[t] = __builtin_amdgcn_mfma_f32_16x16x32_bf16(afr[kc], b, acc[t], 0, 0, 0);
            }
        __syncthreads();                            // all Bt reads done
#pragma unroll
        for (int t = 0; t < 8; ++t)                 // scatter hx -> Bt rows 0..63
#pragma unroll
            for (int r = 0; r < 4; ++r)
                Bt[(rowBase + lq * 4 + r) * 136 + t * 16 + lr] = f2b(acc[t][r]);
#pragma unroll
        for (int j = 0; j < 4; ++j)                 // hb regs -> rows 64..127
            ((float4*)hbf)[tid + j * 256] = hbreg[j];
        __syncthreads();                            // hx + hb ready

        const float b2v = b2f(pw[PK_MLB2 + p]);
        float sabs[8], wh = 0.f;
#pragma unroll
        for (int j = 0; j < 8; ++j) sabs[j] = 0.f;

#pragma unroll 4
        for (int kp = 0; kp < 64; ++kp) {
            const unsigned hx2 = *(const unsigned*)&Bt[myrow * 136 + kp * 2];
            union { unsigned u; float f; } u0, u1;
            u0.u = hx2 << 16;
            u1.u = hx2 & 0xffff0000u;
            const float f0 = u0.f, f1 = u1.f;
            const float2 hw2 = *(const float2*)&hws[kp * 2];
            wh = fmaf(hw2.x, f0, wh);
            wh = fmaf(hw2.y, f1, wh);
            const float4 c00 = *(const float4*)&hbf[(kp * 2) * NA + a0];
            const float4 c01 = *(const float4*)&hbf[(kp * 2) * NA + a0 + 4];
            const float4 c10 = *(const float4*)&hbf[(kp * 2 + 1) * NA + a0];
            const float4 c11 = *(const float4*)&hbf[(kp * 2 + 1) * NA + a0 + 4];
            sabs[0] = fmaf(hw2.x, fabsf(f0 + c00.x), sabs[0]);
            sabs[1] = fmaf(hw2.x, fabsf(f0 + c00.y), sabs[1]);
            sabs[2] = fmaf(hw2.x, fabsf(f0 + c00.z), sabs[2]);
            sabs[3] = fmaf(hw2.x, fabsf(f0 + c00.w), sabs[3]);
            sabs[4] = fmaf(hw2.x, fabsf(f0 + c01.x), sabs[4]);
            sabs[5] = fmaf(hw2.x, fabsf(f0 + c01.y), sabs[5]);
            sabs[6] = fmaf(hw2.x, fabsf(f0 + c01.z), sabs[6]);
            sabs[7] = fmaf(hw2.x, fabsf(f0 + c01.w), sabs[7]);
            sabs[0] = fmaf(hw2.y, fabsf(f1 + c10.x), sabs[0]);
            sabs[1] = fmaf(hw2.y, fabsf(f1 + c10.y), sabs[1]);
            sabs[2] = fmaf(hw2.y, fabsf(f1 + c10.z), sabs[2]);
            sabs[3] = fmaf(hw2.y, fabsf(f1 + c10.w), sabs[3]);
            sabs[4] = fmaf(hw2.y, fabsf(f1 + c11.x), sabs[4]);
            sabs[5] = fmaf(hw2.y, fabsf(f1 + c11.y), sabs[5]);
            sabs[6] = fmaf(hw2.y, fabsf(f1 + c11.z), sabs[6]);
            sabs[7] = fmaf(hw2.y, fabsf(f1 + c11.w), sabs[7]);
        }
#pragma unroll
        for (int j = 0; j < 8; ++j) {
            const float s = wh + wcs[a0 + j] + b2v + sabs[j];
            adjacc[j] += 0.25f / (1.f + __expf(-s));
        }
    }

    // ---- epilogue 1: adj store + rowsum (adjacc intact) ----
    const int grow = row0 + myrow;
    if (grow >= NN) {
#pragma unroll
        for (int j = 0; j < 8; ++j) adjacc[j] = 0.f;
    }
    if (grow < NN) {
        float* dst = adj + (size_t)grow * NA + a0;
        *(float4*)dst = make_float4(adjacc[0], adjacc[1], adjacc[2], adjacc[3]);
        *(float4*)(dst + 4) = make_float4(adjacc[4], adjacc[5], adjacc[6], adjacc[7]);
    }
    float rs = 0.f;
#pragma unroll
    for (int j = 0; j < 8; ++j) rs += adjacc[j];
    rs += __shfl_xor(rs, 1);
    rs += __shfl_xor(rs, 2);
    if (g == 0 && grow < NN) rowsum[grow] = rs;
    __syncthreads();                     // last p's Bt/hbf reads done
    // ---- epilogue 2: stage h tile (from afr) + adjT into dead LDS ----
#pragma unroll
    for (int kc = 0; kc < 4; ++kc)
        *(bf16x8*)&Bt[(rowBase + lr) * 136 + kc * 32 + lq * 8] = afr[kc];
    float* adjTe = (float*)&Bt[64 * 136];          // [64][33] floats (8448B)
#pragma unroll
    for (int j = 0; j < 8; ++j)
        adjTe[myrow * 33 + a0 + j] = adjacc[j];
    // ---- epilogue 3: colsum partials (butterfly destroys adjacc) ----
#pragma unroll
    for (int st = 4; st <= 32; st <<= 1)
#pragma unroll
        for (int j = 0; j < 8; ++j) adjacc[j] += __shfl_xor(adjacc[j], st);
    if (lane < 4) {
#pragma unroll
        for (int j = 0; j < 8; ++j) swr[wv][lane * 8 + j] = adjacc[j];
    }
    __syncthreads();                     // swr + h-tile + adjT ready
    if (tid < NA)
        csPart[tid * NBLK + blockIdx.x] =
            swr[0][tid] + swr[1][tid] + swr[2][tid] + swr[3][tid];
    // ---- epilogue 4: part[b] = adjT^T @ h_tile  (hop-0 aggT, fused) ----
    const int aA = (tid & 15) * 2, kA = (tid >> 4) * 8;
    float acc2[2][8];
#pragma unroll
    for (int ia = 0; ia < 2; ++ia)
#pragma unroll
        for (int j = 0; j < 8; ++j) acc2[ia][j] = 0.f;
#pragma unroll 4
    for (int n = 0; n < TM; ++n) {
        const float a0v = adjTe[n * 33 + aA], a1v = adjTe[n * 33 + aA + 1];
        ushort4 u0 = *(const ushort4*)&Bt[n * 136 + kA];
        ushort4 u1 = *(const ushort4*)&Bt[n * 136 + kA + 4];
        float sv[8] = {b2f(u0.x), b2f(u0.y), b2f(u0.z), b2f(u0.w),
                       b2f(u1.x), b2f(u1.y), b2f(u1.z), b2f(u1.w)};
#pragma unroll
        for (int j = 0; j < 8; ++j) {
            acc2[0][j] += a0v * sv[j];
            acc2[1][j] += a1v * sv[j];
        }
    }
    float* pdst = part + (size_t)blockIdx.x * (NA * HID);
#pragma unroll
    for (int ia = 0; ia < 2; ++ia) {
        *(float4*)&pdst[(aA + ia) * HID + kA] =
            make_float4(acc2[ia][0], acc2[ia][1], acc2[ia][2], acc2[ia][3]);
        *(float4*)&pdst[(aA + ia) * HID + kA + 4] =
            make_float4(acc2[ia][4], acc2[ia][5], acc2[ia][6], acc2[ia][7]);
    }
}

// T[j] = sum_b part[b][j] (256 blocks x 16 cols). WCS=1: blocks 256..287 also
// reduce csPart columns into colsum (old k_cs_red fused).
template<int WCS>
__global__ __launch_bounds__(256) void k_Tred(const float* __restrict__ part,
                                              float* __restrict__ T,
                                              const float* __restrict__ csPart,
                                              float* __restrict__ colsum) {
    __shared__ float red[256];
    const int tid = threadIdx.x;
    if (WCS && blockIdx.x >= 256) {
        const int a = blockIdx.x - 256;
        float s = 0.f;
        for (int b = tid; b < NBLK; b += 256) s += csPart[a * NBLK + b];
        red[tid] = s;
        __syncthreads();
        for (int st = 128; st > 0; st >>= 1) {
            if (tid < st) red[tid] += red[tid + st];
            __syncthreads();
        }
        if (tid == 0) colsum[a] = red[0];
        return;
    }
    const int jj = tid & 15, bq = tid >> 4;
    const int j = blockIdx.x * 16 + jj;
    float s = 0.f;
#pragma unroll 8
    for (int b = bq; b < NBLK; b += 16) s += part[(size_t)b * (NA * HID) + j];
    red[tid] = s;
    __syncthreads();
    if (bq == 0) {
        float t = 0.f;
#pragma unroll
        for (int q = 0; q < 16; ++q) t += red[q * 16 + jj];
        T[j] = t;
    }
}

// agg[a][n] = sum_j T[a][j] * encW[j][n]  (W^T packed bf16; tiny GEMM)
__global__ __launch_bounds__(128) void k_small(const float* __restrict__ T,
                                               const u16* __restrict__ pw,
                                               const int hop,
                                               float* __restrict__ agg) {
    __shared__ float tr[HID];
    const int a = blockIdx.x, n = threadIdx.x;
    tr[n] = T[a * HID + n];
    __syncthreads();
    const u16* w = pw + PK_ENCWT + hop * HID * HID + n * HID;
    float s = 0.f;
#pragma unroll 4
    for (int j4 = 0; j4 < HID; j4 += 4) {
        ushort4 u = *(const ushort4*)(w + j4);
        s += tr[j4] * b2f(u.x) + tr[j4 + 1] * b2f(u.y) +
             tr[j4 + 2] * b2f(u.z) + tr[j4 + 3] * b2f(u.w);
    }
    agg[a * HID + n] = s;
}

// Fused e2(hop0) + aggT(hop1): xc0 tile computed in-LDS (bf16), never written
// to global; part[b][a][k] = sum_n adjT[n][a]*xc0[n][k]. grid = NBLK, per-tile.
__global__ __launch_bounds__(256) void k_e2a(const float* __restrict__ adj,
                                             const float* __restrict__ rowsum,
                                             const float* __restrict__ colsum,
                                             const float* __restrict__ agg,
                                             const u16* __restrict__ pw,
                                             float* __restrict__ part) {
    __shared__ float aggn[NA][LDA];
    __shared__ float adjT[TM][NA + 1];
    __shared__ __align__(8) u16 xcs[TM * 136];
    __shared__ float csl[NA], rsl[TM];
    const int tid = threadIdx.x;
    const int row0 = blockIdx.x * TM;
    const int n0 = (tid & 31) * 4, m0 = (tid >> 5) * 8;
    const int a0 = (tid & 15) * 2, k0 = (tid >> 4) * 8;

    if (tid < NA) csl[tid] = fmaxf(colsum[tid], EPSS);
    if (tid >= 64 && tid < 128) {
        const int m = tid - 64, g = row0 + m;
        rsl[m] = (g < NN) ? 1.f / fmaxf(rowsum[g], EPSS) : 0.f;
    }
    for (int i = tid; i < TM * NA; i += 256) {
        const int m = i >> 5, a = i & 31, g = row0 + m;
        adjT[m][a] = (g < NN) ? adj[(size_t)g * NA + a] : 0.f;
    }
    __syncthreads();
    for (int i = tid; i < (NA * HID) / 4; i += 256) {
        const int a = i >> 5, k4 = (i & 31) << 2;
        float4 v = *(const float4*)(agg + a * HID + k4);
        const float inv = 1.f / csl[a];
        v.x *= inv; v.y *= inv; v.z *= inv; v.w *= inv;
        *(float4*)&aggn[a][k4] = v;
    }
    float bv[4];
#pragma unroll
    for (int j = 0; j < 4; ++j) bv[j] = b2f(pw[PK_ENCB + n0 + j]);   // hop 0
    __syncthreads();
    // e2 compute: xc0 tile
    float acc[8][4];
#pragma unroll
    for (int i = 0; i < 8; ++i)
#pragma unroll
        for (int j = 0; j < 4; ++j) acc[i][j] = 0.f;
    for (int a = 0; a < NA; ++a) {
        float4 gv = *(const float4*)&aggn[a][n0];
        float gvv[4] = {gv.x, gv.y, gv.z, gv.w};
#pragma unroll
        for (int i = 0; i < 8; ++i) {
            const float av = adjT[m0 + i][a];
#pragma unroll
            for (int j = 0; j < 4; ++j) acc[i][j] += av * gvv[j];
        }
    }
#pragma unroll
    for (int i = 0; i < 8; ++i) {
        const float r = rsl[m0 + i];
        ushort4 o;
        o.x = f2b(fmaxf(r * acc[i][0] + bv[0], 0.f));
        o.y = f2b(fmaxf(r * acc[i][1] + bv[1], 0.f));
        o.z = f2b(fmaxf(r * acc[i][2] + bv[2], 0.f));
        o.w = f2b(fmaxf(r * acc[i][3] + bv[3], 0.f));
        *(ushort4*)&xcs[(m0 + i) * 136 + n0] = o;
    }
    __syncthreads();                         // xcs ready
    // aggT phase: part[b] = adjT^T @ xc0  (invalid rows: adjT=0 -> no contrib)
    float acc2[2][8];
#pragma unroll
    for (int ia = 0; ia < 2; ++ia)
#pragma unroll
        for (int j = 0; j < 8; ++j) acc2[ia][j] = 0.f;
#pragma unroll 4
    for (int n = 0; n < TM; ++n) {
        const float a0v = adjT[n][a0], a1v = adjT[n][a0 + 1];
        ushort4 u0 = *(const ushort4*)&xcs[n * 136 + k0];
        ushort4 u1 = *(const ushort4*)&xcs[n * 136 + k0 + 4];
        float sv[8] = {b2f(u0.x), b2f(u0.y), b2f(u0.z), b2f(u0.w),
                       b2f(u1.x), b2f(u1.y), b2f(u1.z), b2f(u1.w)};
#pragma unroll
        for (int j = 0; j < 8; ++j) {
            acc2[0][j] += a0v * sv[j];
            acc2[1][j] += a1v * sv[j];
        }
    }
    float* dst = part + (size_t)blockIdx.x * (NA * HID);
#pragma unroll
    for (int ia = 0; ia < 2; ++ia) {
        *(float4*)&dst[(a0 + ia) * HID + k0] =
            make_float4(acc2[ia][0], acc2[ia][1], acc2[ia][2], acc2[ia][3]);
        *(float4*)&dst[(a0 + ia) * HID + k0 + 4] =
            make_float4(acc2[ia][4], acc2[ia][5], acc2[ia][6], acc2[ia][7]);
    }
}

// Fused e2(hop1) + final: xc1 computed in registers (fp32, never materialized),
// z = LN(xc1 + h) -> out z; pred = prelu(z@w1+b1)@w2+b2 (MFMA).
__global__ __launch_bounds__(256) void k_e2f(const float* __restrict__ adj,
                                             const float* __restrict__ rowsum,
                                             const float* __restrict__ colsum,
                                             const float* __restrict__ agg,
                                             const u16* __restrict__ pw,
                                             float* __restrict__ out) {
    __shared__ __align__(16) u16 As[64 * 136];       // aggn(A) -> z bf16 -> t1
    __shared__ __align__(16) u16 uniB[128 * 136];    // adjT(A) -> zT fp32 -> Bt
    __shared__ float smu[TM], sinv[TM], sg[HID], sb[HID], w2s[2 * HID];
    __shared__ float csl[NA], rsl[TM];
    float* aggn  = (float*)As;       // [NA][LDA] 16.9KB <= 17.4KB
    float* adjTf = (float*)uniB;     // [TM][NA+1] 8.4KB
    float* zT    = (float*)uniB;     // [64][132] fp32 (phase B)
    const int tid = threadIdx.x;
    const int row0 = blockIdx.x * TM;
    const int lane = tid & 63, wv = tid >> 6, rowBase = wv * 16;
    const int lr = lane & 15, lq = lane >> 4;
    const int n0 = (tid & 31) * 4, m0 = (tid >> 5) * 8;
    const float* h = out + Z_OFF;

    // ---- phase A: e2 hop 1 ----
    if (tid < NA) csl[tid] = fmaxf(colsum[tid], EPSS);
    if (tid >= 64 && tid < 128) {
        const int m = tid - 64, g = row0 + m;
        rsl[m] = (g < NN) ? 1.f / fmaxf(rowsum[g], EPSS) : 0.f;
    }
    for (int i = tid; i < TM * NA; i += 256) {
        const int m = i >> 5, a = i & 31, g = row0 + m;
        adjTf[m * (NA + 1) + a] = (g < NN) ? adj[(size_t)g * NA + a] : 0.f;
    }
    __syncthreads();
    for (int i = tid; i < (NA * HID) / 4; i += 256) {
        const int a = i >> 5, k4 = (i & 31) << 2;
        float4 v = *(const float4*)(agg + a * HID + k4);
        const float inv = 1.f / csl[a];
        v.x *= inv; v.y *= inv; v.z *= inv; v.w *= inv;
        *(float4*)&aggn[a * LDA + k4] = v;
    }
    __syncthreads();
    float acc[8][4];
#pragma unroll
    for (int i = 0; i < 8; ++i)
#pragma unroll
        for (int j = 0; j < 4; ++j) acc[i][j] = 0.f;
    for (int a = 0; a < NA; ++a) {
        float4 gv = *(const float4*)&aggn[a * LDA + n0];
        float gvv[4] = {gv.x, gv.y, gv.z, gv.w};
#pragma unroll
        for (int i = 0; i < 8; ++i) {
            const float av = adjTf[(m0 + i) * (NA + 1) + a];
#pragma unroll
            for (int j = 0; j < 4; ++j) acc[i][j] += av * gvv[j];
        }
    }
    float bv[4];
#pragma unroll
    for (int j = 0; j < 4; ++j) bv[j] = b2f(pw[PK_ENCB + HID + n0 + j]);  // hop 1
    float xcv[8][4];
#pragma unroll
    for (int i = 0; i < 8; ++i) {
        const float r = rsl[m0 + i];
#pragma unroll
        for (int j = 0; j < 4; ++j)
            xcv[i][j] = fmaxf(r * acc[i][j] + bv[j], 0.f);
    }
    __syncthreads();                     // aggn/adjT reads done
    // ---- phase B: zT = xc1 + h ----
#pragma unroll
    for (int i = 0; i < 8; ++i) {
        const int g = row0 + m0 + i;
        float4 hv = make_float4(0.f, 0.f, 0.f, 0.f);
        if (g < NN) hv = *(const float4*)(h + (size_t)g * HID + n0);
        float4 zv = make_float4(xcv[i][0] + hv.x, xcv[i][1] + hv.y,
                                xcv[i][2] + hv.z, xcv[i][3] + hv.w);
        *(float4*)&zT[(m0 + i) * 132 + n0] = zv;
    }
    if (tid < HID) { sg[tid] = b2f(pw[PK_LNG + tid]); sb[tid] = b2f(pw[PK_LNB + tid]); }
    w2s[tid] = b2f(pw[PK_CLSW2 + tid]);
    __syncthreads();
    // ---- LN ----
    if (tid < TM) {
        float s = 0.f;
        for (int k = 0; k < HID; ++k) s += zT[tid * 132 + k];
        const float mu = s * (1.f / HID);
        float v = 0.f;
        for (int k = 0; k < HID; ++k) { const float d = zT[tid * 132 + k] - mu; v += d * d; }
        smu[tid] = mu;
        sinv[tid] = rsqrtf(v * (1.f / HID) + LN_EPS);
    }
    __syncthreads();
    for (int i = tid; i < TM * 32; i += 256) {
        const int m = i >> 5, k4 = (i & 31) << 2, g = row0 + m;
        float4 v = *(const float4*)&zT[m * 132 + k4];
        const float mu = smu[m], inv = sinv[m];
        v.x = (v.x - mu) * inv * sg[k4 + 0] + sb[k4 + 0];
        v.y = (v.y - mu) * inv * sg[k4 + 1] + sb[k4 + 1];
        v.z = (v.z - mu) * inv * sg[k4 + 2] + sb[k4 + 2];
        v.w = (v.w - mu) * inv * sg[k4 + 3] + sb[k4 + 3];
        if (g < NN) *(float4*)&out[Z_OFF + (size_t)g * HID + k4] = v;
        ushort4 o; o.x = f2b(v.x); o.y = f2b(v.y); o.z = f2b(v.z); o.w = f2b(v.w);
        *(ushort4*)&As[m * 136 + k4] = o;
    }
    __syncthreads();
    for (int i = tid; i < 128 * 32; i += 256) {
        const int n = i >> 5, k4 = (i & 31) << 2;
        *(ushort4*)&uniB[n * 136 + k4] =
            *(const ushort4*)(pw + PK_CLSW1T + n * 128 + k4);
    }
    __syncthreads();
    f32x4 macc[8];
    const f32x4 z4 = {0.f, 0.f, 0.f, 0.f};
#pragma unroll
    for (int t = 0; t < 8; ++t) macc[t] = z4;
    mfma_64x128(As, uniB, macc, lane, rowBase);
    __syncthreads();
#pragma unroll
    for (int t = 0; t < 8; ++t) {
        const int col = t * 16 + lr;
        const float bc = b2f(pw[PK_CLSB1 + col]);
        const float pa = b2f(pw[PK_PRELU + col]);
#pragma unroll
        for (int r = 0; r < 4; ++r) {
            float v = macc[t][r] + bc;
            v = v > 0.f ? v : pa * v;
            As[(rowBase + lq * 4 + r) * 136 + col] = f2b(v);
        }
    }
    __syncthreads();
    if (tid < 128) {
        const int r = tid >> 1, c = tid & 1, g = row0 + r;
        if (g < NN) {
            float s = b2f(pw[PK_CLSB2 + c]);
            for (int k = 0; k < HID; ++k) s += b2f(As[r * 136 + k]) * w2s[k * 2 + c];
            out[PRED_OFF + (size_t)g * 2 + c] = s;
        }
    }
}

extern "C" void kernel_launch(void* const* d_in, const int* in_sizes, int n_in,
                              void* d_out, int out_size, void* d_ws, size_t ws_size,
                              hipStream_t stream) {
    const bool ok = (n_in >= 19) && (out_size == OUT_TOT) &&
                    (ws_size >= WS_NEED_BYTES) &&
                    (in_sizes[0] == NN * FEAT) && (in_sizes[6] == NP * 2 * HID * HID) &&
                    (in_sizes[10] == 2 * HID * HID) && (in_sizes[17] == HID * 2);
    if (!ok) {
        hipMemsetAsync(d_out, 0, (size_t)OUT_TOT * 4, stream);
        return;
    }

    float* ws    = (float*)d_ws;
    u16*   wsu   = (u16*)d_ws;
    float* out   = (float*)d_out;
    int*   flags = (int*)(ws + FLAG_F);
    float* hbuf  = out + Z_OFF;       // h (fp32) parked in z output region
    u16*   pw    = wsu + PW_U;
    float* xcf   = (float*)(wsu + XC_U);   // dead XC+SUP regions (25.6 MB)
    float* csPart = xcf;                   // 100 KB
    float* partb = xcf + 32768;            // NBLK*4096 floats (12.81 MB)
    float* Tbuf  = ws + HB_F;              // T (4096 floats); hb dead post-attn
    float* wcv   = ws + AGG1_F;            // wc[p][a]: dead until hop-1 small

    P19 pa;
    for (int i = 0; i < 19; ++i) pa.q[i] = d_in[i];
    k_detect_all<<<19, 256, 0, stream>>>(pa, flags);
    k_convT<<<161, 256, 0, stream>>>(pa, flags, pw);   // tiles + vector params

    k_pre<<<NP * NA, 128, 0, stream>>>(d_in[5], d_in[6], d_in[7], d_in[8],
                                       ws + HB_F, wcv, flags);
    k_anchor<<<NA / 2, 256, 0, stream>>>(d_in[5], d_in[14], d_in[15], d_in[16],
                                         d_in[17], d_in[18], out, flags);

    // h = relu(x@W1+b1)@W2+b2 fused; x A-frags in regs, Bt64 halves, 4 blk/CU
    k_gemm2<<<NBLK, 256, 0, stream>>>(d_in[0], pw, hbuf, flags);

    // fused attention + rowsum + colsum partials + hop-0 aggT partials
    k_fattn<<<NBLK, 256, 0, stream>>>(hbuf, pw, ws + HB_F, wcv, ws + ADJ_F,
                                      ws + RS_F, csPart, partb);

    // hop 0: T0-reduce (+colsum fused) ; agg0 = (T0/cs) @ encW0
    k_Tred<1><<<288, 256, 0, stream>>>(partb, Tbuf, csPart, ws + CS_F);
    k_small<<<NA, 128, 0, stream>>>(Tbuf, pw, 0, ws + AGG0_F);
    // fused: xc0 (in-LDS only) + T1 partials
    k_e2a<<<NBLK, 256, 0, stream>>>(ws + ADJ_F, ws + RS_F, ws + CS_F, ws + AGG0_F,
                                    pw, partb);
    k_Tred<0><<<256, 256, 0, stream>>>(partb, Tbuf, csPart, ws + CS_F);
    k_small<<<NA, 128, 0, stream>>>(Tbuf, pw, 1, ws + AGG1_F);
    // fused: xc1 (in-regs only) + LN + classifier
    k_e2f<<<NBLK, 256, 0, stream>>>(ws + ADJ_F, ws + RS_F, ws + CS_F, ws + AGG1_F,
                                    pw, out);
}

// Round 14
// 402.942 us; speedup vs baseline: 1.0109x; 1.0109x over previous
//
#include <hip/hip_runtime.h>
#include <math.h>

#define NN 50000
#define FEAT 256
#define HID 128
#define NA 32
#define NP 4
#define TM 64
#define NBLK 782            // ceil(50000/64)
#define LDA 132
#define EPSS 1e-12f
#define LN_EPS 1e-5f

typedef unsigned short u16;
typedef __attribute__((ext_vector_type(8))) short bf16x8;
typedef __attribute__((ext_vector_type(4))) float f32x4;

// ---- workspace layout (float offsets) ----
#define ADJ_F   0           // adj fp32 (NN*NA)
#define RS_F    1600000
#define CS_F    1650000
#define AGG0_F  1650032
#define AGG1_F  1654128
#define HB_F    1658256     // hb[p][k][a] fp32 (16384); later reused for T (4096)
#define FLAG_F  1674640     // int flags[19] (pad 32)
#define F_END   1674672
// ---- u16 offsets ----
#define XC_U   (2 * F_END)            // 3349344
#define SUP_U  (XC_U + NN * HID)      // 9749344
#define PW_U   (SUP_U + NN * HID)     // 16149344
#define PW_TOT 165638
#define WS_NEED_BYTES ((size_t)(PW_U + PW_TOT) * 2ULL)
// The XC and SUP regions (25.6 MB contiguous) are permanently dead as named
// buffers (sup/t/xc never materialized). Scratch carved from them:
//   csPart: XC_U + 0      (NA*NBLK floats, 100 KB)
//   partb : XC_U + 128KB  (NBLK*4096 floats = 12.81 MB, spans into SUP)
// wc[p][a] (128 floats) aliases AGG1_F: written by k_pre, consumed by k_fattn;
// k_small hop-1 overwrites AGG1_F long after attention is done.

// ---- packed bf16 weights; matrices stored TRANSPOSED [n][k] ----
#define PK_IMW1T  0         // 128x256
#define PK_IMW2T  32768     // 128x128
#define PK_MLW1T  49152     // 4 x (128x128)  (Wx^T only)
#define PK_ENCWT  114688    // 2 x (128x128)
#define PK_CLSW1T 147456    // 128x128
#define PK_IMB1   163840
#define PK_IMB2   163968
#define PK_MLW2   164096    // 4x128
#define PK_ENCB   164608    // 2x128
#define PK_LNG    164864
#define PK_LNB    164992
#define PK_CLSB1  165120
#define PK_PRELU  165248
#define PK_CLSW2  165376    // 128x2
#define PK_CLSB2  165632
#define PK_MLB2   165634
#define PK_TOTAL  165638

// ---- output layout (fp32 element offsets) ----
#define PRED_OFF 0
#define Z_OFF    100000
#define AV_OFF   6500000
#define AL_OFF   6504096
#define OUT_TOT  6504160

__device__ __constant__ int kNel[19] = {
    NN * FEAT, FEAT * HID, HID, HID * HID, HID, NA * HID,
    NP * 2 * HID * HID, NP * HID, NP * HID, NP, 2 * HID * HID, 2 * HID,
    HID, HID, HID * HID, HID, HID, HID * 2, 2};

// transposed-matrix convert segments (seg 0: K=256, 32 tiles; segs 1-8: K=128,
// 16 tiles each; 160 tiles total, 32x32 each)
__device__ __constant__ int tDst[9]  = {PK_IMW1T,PK_IMW2T,PK_MLW1T,PK_MLW1T+16384,
                                        PK_MLW1T+32768,PK_MLW1T+49152,PK_ENCWT,
                                        PK_ENCWT+16384,PK_CLSW1T};
__device__ __constant__ int tSrcT[9] = {1,3,6,6,6,6,10,10,14};
__device__ __constant__ int tBase[9] = {0,0,0,32768,65536,98304,0,16384,0};
// vector convert segments
#define VSEG_TOT 1798
__device__ __constant__ int vLen[11] = {128,128,512,256,128,128,128,128,256,2,4};
__device__ __constant__ int vDst[11] = {PK_IMB1,PK_IMB2,PK_MLW2,PK_ENCB,PK_LNG,PK_LNB,
                                        PK_CLSB1,PK_PRELU,PK_CLSW2,PK_CLSB2,PK_MLB2};
__device__ __constant__ int vSrcT[11]= {2,4,8,11,12,13,15,16,17,18,9};

struct P19 { const void* q[19]; };

__device__ __forceinline__ float b2f(u16 u) {
    union { float f; unsigned int i; } v; v.i = ((unsigned int)u) << 16; return v.f;
}
__device__ __forceinline__ u16 f2b(float f) {
    union { float f; unsigned int i; } v; v.f = f;
    unsigned int x = v.i;
    x += 0x7fffu + ((x >> 16) & 1u);   // RNE
    return (u16)(x >> 16);
}
// flag: 0 = bf16, 1 = fp32, 2 = all-zero
__device__ __forceinline__ float ldf(const void* p, size_t i, int fl) {
    if (fl == 1) return ((const float*)p)[i];
    if (fl == 0) return b2f(((const u16*)p)[i]);
    return 0.f;
}

// ---- per-tensor dtype detector (first min(N,8192) u16s only) ----
__global__ __launch_bounds__(256) void k_detect_all(P19 a, int* __restrict__ flags) {
    __shared__ int sHi[256], sE[256], sO[256];
    const int b = blockIdx.x;
    const u16* p = (const u16*)a.q[b];
    const int M = (kNel[b] < 8192) ? kNel[b] : 8192;
    int cHi = 0, cE = 0, cO = 0;
    for (int j = threadIdx.x; j < M; j += 256) {
        const u16 v = p[j];
        if (j & 1) cO += (v != 0);
        else { cE += (v != 0); cHi += (((v >> 7) & 0xFF) >= 200); }
    }
    sHi[threadIdx.x] = cHi; sE[threadIdx.x] = cE; sO[threadIdx.x] = cO;
    __syncthreads();
    for (int s = 128; s > 0; s >>= 1) {
        if (threadIdx.x < (unsigned)s) {
            sHi[threadIdx.x] += sHi[threadIdx.x + s];
            sE[threadIdx.x]  += sE[threadIdx.x + s];
            sO[threadIdx.x]  += sO[threadIdx.x + s];
        }
        __syncthreads();
    }
    if (threadIdx.x == 0) {
        int f;
        if (sE[0] == 0 && sO[0] == 0) f = 2;
        else if (sHi[0] >= 4 || sE[0] == 0) f = 1;
        else f = 0;
        flags[b] = f;
    }
}

// ---- pack weights: 32x32 LDS tile-transpose (coalesced src reads AND dst
// writes). pw[dst + n*K + k] = src[base + k*128 + n]. Block 160 = vector params.
__global__ __launch_bounds__(256) void k_convT(P19 a, const int* __restrict__ flags,
                                               u16* __restrict__ pw) {
    const int b = blockIdx.x;
    if (b == 160) {                      // vector params (old k_convV)
        for (int idx = threadIdx.x; idx < VSEG_TOT; idx += 256) {
            int off = idx, s = 0;
            while (off >= vLen[s]) { off -= vLen[s]; ++s; }
            const int si = vSrcT[s];
            pw[vDst[s] + off] = f2b(ldf(a.q[si], off, flags[si]));
        }
        return;
    }
    __shared__ float tle[32][33];
    int s, t;
    if (b < 32) { s = 0; t = b; }
    else        { s = 1 + (b - 32) / 16; t = (b - 32) % 16; }
    const int K = (s == 0) ? 256 : 128;
    const int tn = (t & 3) * 32, tk = (t >> 2) * 32;
    const int si = tSrcT[s], fl = flags[si];
    const int c0 = threadIdx.x & 31, q0 = threadIdx.x >> 5;
#pragma unroll
    for (int i = 0; i < 4; ++i) {
        const int kk = q0 + i * 8;
        tle[kk][c0] = ldf(a.q[si],
                          (size_t)tBase[s] + (size_t)(tk + kk) * 128 + tn + c0, fl);
    }
    __syncthreads();
#pragma unroll
    for (int i = 0; i < 4; ++i) {
        const int nn = q0 + i * 8;
        pw[tDst[s] + (size_t)(tn + nn) * K + tk + c0] = f2b(tle[c0][nn]);
    }
}

// ---- MFMA core: 64x128 tile, wave wv handles rows wv*16..+16, all 128 cols.
__device__ __forceinline__ void mfma_64x128(const u16* As, const u16* Bt,
                                            f32x4 acc[8], int lane, int rowBase) {
    const int lr = lane & 15, lq = lane >> 4;
#pragma unroll
    for (int kc = 0; kc < 4; ++kc) {
        bf16x8 a = *(const bf16x8*)(As + (rowBase + lr) * 136 + kc * 32 + lq * 8);
#pragma unroll
        for (int t = 0; t < 8; ++t) {
            bf16x8 b = *(const bf16x8*)(Bt + (t * 16 + lr) * 136 + kc * 32 + lq * 8);
            acc[t] = __builtin_amdgcn_mfma_f32_16x16x32_bf16(a, b, acc[t], 0, 0, 0);
        }
    }
}

// ---- Fused im MLP v2: h = relu(x@W1+b1)@W2+b2. x A-fragments in regs (fattn
// pattern); B staged in 64-row halves (Bt 64x136). LDS 34.8KB -> 4 blocks/CU.
__global__ __launch_bounds__(256) void k_gemm2(const void* __restrict__ A,
                                               const u16* __restrict__ pw,
                                               float* __restrict__ outh,
                                               const int* __restrict__ flags) {
    __shared__ __align__(16) u16 As[64 * 136];   // t tile (pass-2 A operand)
    __shared__ __align__(16) u16 Bt[64 * 136];   // B half staging
    const int fA = flags[0];
    const int tid = threadIdx.x;
    const int row0 = blockIdx.x * TM;
    const int lane = tid & 63, wv = tid >> 6, rowBase = wv * 16;
    const int lr = lane & 15, lq = lane >> 4;

    // x A-fragments (8 k-chunks of 32), fp32/bf16 -> bf16 regs
    bf16x8 ax[8];
    {
        const int gr = row0 + rowBase + lr;
#pragma unroll
        for (int kc = 0; kc < 8; ++kc) {
            bf16x8 t;
            if (gr < NN) {
                const size_t idx = (size_t)gr * FEAT + kc * 32 + lq * 8;
                if (fA == 1) {
                    const float* src = (const float*)A + idx;
                    float4 v0 = *(const float4*)src;
                    float4 v1 = *(const float4*)(src + 4);
                    t[0] = (short)f2b(v0.x); t[1] = (short)f2b(v0.y);
                    t[2] = (short)f2b(v0.z); t[3] = (short)f2b(v0.w);
                    t[4] = (short)f2b(v1.x); t[5] = (short)f2b(v1.y);
                    t[6] = (short)f2b(v1.z); t[7] = (short)f2b(v1.w);
                } else {
                    t = *(const bf16x8*)((const u16*)A + idx);
                }
            } else {
#pragma unroll
                for (int j = 0; j < 8; ++j) t[j] = 0;
            }
            ax[kc] = t;
        }
    }

    f32x4 acc[8];
    const f32x4 z4 = {0.f, 0.f, 0.f, 0.f};
#pragma unroll
    for (int t = 0; t < 8; ++t) acc[t] = z4;

    // pass 1: t = relu(x@W1+b1); 2 n-halves x 2 K-chunks, Bt64 staging
    for (int half = 0; half < 2; ++half) {
        for (int kc2 = 0; kc2 < 2; ++kc2) {
            __syncthreads();                 // prev Bt reads done
            for (int i = tid; i < 64 * 32; i += 256) {
                const int n = i >> 5, k4 = (i & 31) << 2;
                *(ushort4*)&Bt[n * 136 + k4] =
                    *(const ushort4*)(pw + PK_IMW1T +
                                      (size_t)(half * 64 + n) * FEAT + kc2 * 128 + k4);
            }
            __syncthreads();                 // Bt ready
#pragma unroll
            for (int kc = 0; kc < 4; ++kc)
#pragma unroll
                for (int tt = 0; tt < 4; ++tt) {
                    bf16x8 b = *(const bf16x8*)(Bt + (tt * 16 + lr) * 136 + kc * 32 + lq * 8);
                    acc[half * 4 + tt] = __builtin_amdgcn_mfma_f32_16x16x32_bf16(
                        ax[kc2 * 4 + kc], b, acc[half * 4 + tt], 0, 0, 0);
                }
        }
    }
    // t tile (relu + b1, bf16) scattered into As
#pragma unroll
    for (int t = 0; t < 8; ++t) {
        const int col = t * 16 + lr;
        const float bv = b2f(pw[PK_IMB1 + col]);
#pragma unroll
        for (int r = 0; r < 4; ++r)
            As[(rowBase + lq * 4 + r) * 136 + col] = f2b(fmaxf(acc[t][r] + bv, 0.f));
    }
    // pass 2: h = t@W2+b2; 2 n-halves, Bt64 staging; A-frags from As
    f32x4 acc2[8];
#pragma unroll
    for (int t = 0; t < 8; ++t) acc2[t] = z4;
    for (int half = 0; half < 2; ++half) {
        __syncthreads();                     // prev Bt reads done + As writes done
        for (int i = tid; i < 64 * 32; i += 256) {
            const int n = i >> 5, k4 = (i & 31) << 2;
            *(ushort4*)&Bt[n * 136 + k4] =
                *(const ushort4*)(pw + PK_IMW2T + (size_t)(half * 64 + n) * HID + k4);
        }
        __syncthreads();                     // Bt ready
#pragma unroll
        for (int kc = 0; kc < 4; ++kc) {
            bf16x8 a = *(const bf16x8*)(As + (rowBase + lr) * 136 + kc * 32 + lq * 8);
#pragma unroll
            for (int tt = 0; tt < 4; ++tt) {
                bf16x8 b = *(const bf16x8*)(Bt + (tt * 16 + lr) * 136 + kc * 32 + lq * 8);
                acc2[half * 4 + tt] = __builtin_amdgcn_mfma_f32_16x16x32_bf16(
                    a, b, acc2[half * 4 + tt], 0, 0, 0);
            }
        }
    }
#pragma unroll
    for (int t = 0; t < 8; ++t) {
        const int col = t * 16 + lr;
        const float bv = b2f(pw[PK_IMB2 + col]);
#pragma unroll
        for (int r = 0; r < 4; ++r) {
            const int g = row0 + rowBase + lq * 4 + r;
            if (g < NN) outh[(size_t)g * HID + col] = acc2[t][r] + bv;
        }
    }
}

// hb[p][k][a] = (anchors @ Wa[p] + ml_b1[p]) transposed; also reduces
// wc[p][a] = sum_k 0.5*w2[p][k]*hb[p][k][a] in-block (old k_wc fused).
__global__ __launch_bounds__(128) void k_pre(const void* __restrict__ anchors,
                                             const void* __restrict__ ml_w1,
                                             const void* __restrict__ ml_b1,
                                             const void* __restrict__ ml_w2,
                                             float* __restrict__ hb,
                                             float* __restrict__ wc,
                                             const int* __restrict__ flags) {
    __shared__ float sa[HID];
    __shared__ float red[128];
    const int fAn = flags[5], fW1 = flags[6], fB1 = flags[7], fW2 = flags[8];
    const int p = blockIdx.x >> 5, a = blockIdx.x & 31, k = threadIdx.x;
    sa[k] = ldf(anchors, a * HID + k, fAn);
    __syncthreads();
    float acc = ldf(ml_b1, p * HID + k, fB1);
    const size_t wbase = ((size_t)p * 2 * HID + HID) * HID + k;
#pragma unroll 4
    for (int j = 0; j < HID; ++j)
        acc += sa[j] * ldf(ml_w1, wbase + (size_t)j * HID, fW1);
    hb[p * (NA * HID) + k * NA + a] = acc;
    red[k] = 0.5f * ldf(ml_w2, p * HID + k, fW2) * acc;
    __syncthreads();
    for (int st = 64; st > 0; st >>= 1) {
        if (k < st) red[k] += red[k + st];
        __syncthreads();
    }
    if (k == 0) wc[p * NA + a] = red[0];
}

// anchor classifier + anchor_vec copy (fp32 outputs, raw inputs via flags)
__global__ __launch_bounds__(256) void k_anchor(const void* __restrict__ anchors,
                                                const void* __restrict__ cls_w1,
                                                const void* __restrict__ cls_b1,
                                                const void* __restrict__ prelu_a,
                                                const void* __restrict__ cls_w2,
                                                const void* __restrict__ cls_b2,
                                                float* __restrict__ out,
                                                const int* __restrict__ flags) {
    __shared__ float sa[2][HID];
    __shared__ float st1[2][HID];
    const int fAn = flags[5], fW1 = flags[14], fB1 = flags[15];
    const int fPa = flags[16], fW2 = flags[17], fB2 = flags[18];
    const int tid = threadIdx.x;
    const int a0 = blockIdx.x * 2;
    const int half = tid >> 7, k = tid & 127;
    sa[half][k] = ldf(anchors, (a0 + half) * HID + k, fAn);
    __syncthreads();
    float acc = ldf(cls_b1, k, fB1);
#pragma unroll 4
    for (int j = 0; j < HID; ++j) acc += sa[half][j] * ldf(cls_w1, j * HID + k, fW1);
    const float pa = ldf(prelu_a, k, fPa);
    st1[half][k] = acc > 0.f ? acc : pa * acc;
    __syncthreads();
    if (tid < 4) {
        const int aa = tid >> 1, c = tid & 1;
        float s = ldf(cls_b2, c, fB2);
        for (int j = 0; j < HID; ++j) s += st1[aa][j] * ldf(cls_w2, j * 2 + c, fW2);
        out[AL_OFF + (a0 + aa) * 2 + c] = s;
    }
    if (blockIdx.x == 0) {
        for (int i = tid; i < NA * HID; i += 256)
            out[AV_OFF + i] = ldf(anchors, i, fAn);
    }
}

// Fused attention v6 (reverted to round-12 best): hb staged at use-point;
// hop-0 aggT (part = adjT^T @ h) fused into the epilogue (afr fragments,
// dead Bt/hbf LDS). LDS 36KB -> 4 blocks/CU. Writes adj, rowsum, csPart, part.
__global__ __launch_bounds__(256) void k_fattn(const float* __restrict__ h,
                                               const u16* __restrict__ pw,
                                               const float* __restrict__ hb,
                                               const float* __restrict__ wc,
                                               float* __restrict__ adj,
                                               float* __restrict__ rowsum,
                                               float* __restrict__ csPart,
                                               float* __restrict__ part) {
    __shared__ __align__(16) u16 Bt[128 * 136];   // Wx^T -> {hx 0-63, hb(f32) 64-127}
    __shared__ float hws[HID];
    __shared__ float wcs[NA];
    __shared__ float swr[4][NA];
    float* hbf = (float*)&Bt[64 * 136];           // 4352 floats capacity, 4096 used
    const int tid = threadIdx.x;
    const int row0 = blockIdx.x * TM;
    const int lane = tid & 63, wv = tid >> 6, rowBase = wv * 16;
    const int lr = lane & 15, lq = lane >> 4;
    const int g = tid & 3, myrow = tid >> 2;        // 4 anchor-groups x 64 rows
    const int a0 = g * 8;

    // A-fragments (h tile, fp32->bf16) held in regs; identical for all 4 p's
    bf16x8 afr[4];
    {
        const int gr = row0 + rowBase + lr;
#pragma unroll
        for (int kc = 0; kc < 4; ++kc) {
            bf16x8 t;
            if (gr < NN) {
                const float* src = h + (size_t)gr * HID + kc * 32 + lq * 8;
                float4 v0 = *(const float4*)src;
                float4 v1 = *(const float4*)(src + 4);
                t[0] = (short)f2b(v0.x); t[1] = (short)f2b(v0.y);
                t[2] = (short)f2b(v0.z); t[3] = (short)f2b(v0.w);
                t[4] = (short)f2b(v1.x); t[5] = (short)f2b(v1.y);
                t[6] = (short)f2b(v1.z); t[7] = (short)f2b(v1.w);
            } else {
#pragma unroll
                for (int j = 0; j < 8; ++j) t[j] = 0;
            }
            afr[kc] = t;
        }
    }

    float adjacc[8];
#pragma unroll
    for (int j = 0; j < 8; ++j) adjacc[j] = 0.f;

    for (int p = 0; p < NP; ++p) {
        __syncthreads();                            // prev p's LDS reads done
        for (int i = tid; i < 128 * 32; i += 256) { // Wx^T -> Bt
            const int n = i >> 5, k4 = (i & 31) << 2;
            *(ushort4*)&Bt[n * 136 + k4] =
                *(const ushort4*)(pw + PK_MLW1T + p * 16384 + n * 128 + k4);
        }
        if (tid < HID) hws[tid] = 0.5f * b2f(pw[PK_MLW2 + p * HID + tid]);
        if (tid < NA) wcs[tid] = wc[p * NA + tid];
        __syncthreads();                            // Bt/hws/wcs ready

        f32x4 acc[8];
        const f32x4 z4 = {0.f, 0.f, 0.f, 0.f};
#pragma unroll
        for (int t = 0; t < 8; ++t) acc[t] = z4;
#pragma unroll
        for (int kc = 0; kc < 4; ++kc)
#pragma unroll
            for (int t = 0; t < 8; ++t) {
                bf16x8 b = *(const bf16x8*)(Bt + (t * 16 + lr) * 136 + kc * 32 + lq * 8);
                acc[t] = __builtin_amdgcn_mfma_f32_16x16x32_bf16(afr[kc], b, acc[t], 0, 0, 0);
            }
        __syncthreads();                            // all Bt reads done
#pragma unroll
        for (int t = 0; t < 8; ++t)                 // scatter hx -> Bt rows 0..63
#pragma unroll
            for (int r = 0; r < 4; ++r)
                Bt[(rowBase + lq * 4 + r) * 136 + t * 16 + lr] = f2b(acc[t][r]);
        {   // hb -> rows 64..127 (use-point load: no VGPR carry across MFMA)
            const float4* hbp4 = (const float4*)(hb + (size_t)p * (NA * HID));
#pragma unroll
            for (int j = 0; j < 4; ++j)
                ((float4*)hbf)[tid + j * 256] = hbp4[tid + j * 256];
        }
        __syncthreads();                            // hx + hb ready

        const float b2v = b2f(pw[PK_MLB2 + p]);
        float sabs[8], wh = 0.f;
#pragma unroll
        for (int j = 0; j < 8; ++j) sabs[j] = 0.f;

#pragma unroll 4
        for (int kp = 0; kp < 64; ++kp) {
            const unsigned hx2 = *(const unsigned*)&Bt[myrow * 136 + kp * 2];
            union { unsigned u; float f; } u0, u1;
            u0.u = hx2 << 16;
            u1.u = hx2 & 0xffff0000u;
            const float f0 = u0.f, f1 = u1.f;
            const float2 hw2 = *(const float2*)&hws[kp * 2];
            wh = fmaf(hw2.x, f0, wh);
            wh = fmaf(hw2.y, f1, wh);
            const float4 c00 = *(const float4*)&hbf[(kp * 2) * NA + a0];
            const float4 c01 = *(const float4*)&hbf[(kp * 2) * NA + a0 + 4];
            const float4 c10 = *(const float4*)&hbf[(kp * 2 + 1) * NA + a0];
            const float4 c11 = *(const float4*)&hbf[(kp * 2 + 1) * NA + a0 + 4];
            sabs[0] = fmaf(hw2.x, fabsf(f0 + c00.x), sabs[0]);
            sabs[1] = fmaf(hw2.x, fabsf(f0 + c00.y), sabs[1]);
            sabs[2] = fmaf(hw2.x, fabsf(f0 + c00.z), sabs[2]);
            sabs[3] = fmaf(hw2.x, fabsf(f0 + c00.w), sabs[3]);
            sabs[4] = fmaf(hw2.x, fabsf(f0 + c01.x), sabs[4]);
            sabs[5] = fmaf(hw2.x, fabsf(f0 + c01.y), sabs[5]);
            sabs[6] = fmaf(hw2.x, fabsf(f0 + c01.z), sabs[6]);
            sabs[7] = fmaf(hw2.x, fabsf(f0 + c01.w), sabs[7]);
            sabs[0] = fmaf(hw2.y, fabsf(f1 + c10.x), sabs[0]);
            sabs[1] = fmaf(hw2.y, fabsf(f1 + c10.y), sabs[1]);
            sabs[2] = fmaf(hw2.y, fabsf(f1 + c10.z), sabs[2]);
            sabs[3] = fmaf(hw2.y, fabsf(f1 + c10.w), sabs[3]);
            sabs[4] = fmaf(hw2.y, fabsf(f1 + c11.x), sabs[4]);
            sabs[5] = fmaf(hw2.y, fabsf(f1 + c11.y), sabs[5]);
            sabs[6] = fmaf(hw2.y, fabsf(f1 + c11.z), sabs[6]);
            sabs[7] = fmaf(hw2.y, fabsf(f1 + c11.w), sabs[7]);
        }
#pragma unroll
        for (int j = 0; j < 8; ++j) {
            const float s = wh + wcs[a0 + j] + b2v + sabs[j];
            adjacc[j] += 0.25f / (1.f + __expf(-s));
        }
    }

    // ---- epilogue 1: adj store + rowsum (adjacc intact) ----
    const int grow = row0 + myrow;
    if (grow >= NN) {
#pragma unroll
        for (int j = 0; j < 8; ++j) adjacc[j] = 0.f;
    }
    if (grow < NN) {
        float* dst = adj + (size_t)grow * NA + a0;
        *(float4*)dst = make_float4(adjacc[0], adjacc[1], adjacc[2], adjacc[3]);
        *(float4*)(dst + 4) = make_float4(adjacc[4], adjacc[5], adjacc[6], adjacc[7]);
    }
    float rs = 0.f;
#pragma unroll
    for (int j = 0; j < 8; ++j) rs += adjacc[j];
    rs += __shfl_xor(rs, 1);
    rs += __shfl_xor(rs, 2);
    if (g == 0 && grow < NN) rowsum[grow] = rs;
    __syncthreads();                     // last p's Bt/hbf reads done
    // ---- epilogue 2: stage h tile (from afr) + adjT into dead LDS ----
#pragma unroll
    for (int kc = 0; kc < 4; ++kc)
        *(bf16x8*)&Bt[(rowBase + lr) * 136 + kc * 32 + lq * 8] = afr[kc];
    float* adjTe = (float*)&Bt[64 * 136];          // [64][33] floats (8448B)
#pragma unroll
    for (int j = 0; j < 8; ++j)
        adjTe[myrow * 33 + a0 + j] = adjacc[j];
    // ---- epilogue 3: colsum partials (butterfly destroys adjacc) ----
#pragma unroll
    for (int st = 4; st <= 32; st <<= 1)
#pragma unroll
        for (int j = 0; j < 8; ++j) adjacc[j] += __shfl_xor(adjacc[j], st);
    if (lane < 4) {
#pragma unroll
        for (int j = 0; j < 8; ++j) swr[wv][lane * 8 + j] = adjacc[j];
    }
    __syncthreads();                     // swr + h-tile + adjT ready
    if (tid < NA)
        csPart[tid * NBLK + blockIdx.x] =
            swr[0][tid] + swr[1][tid] + swr[2][tid] + swr[3][tid];
    // ---- epilogue 4: part[b] = adjT^T @ h_tile  (hop-0 aggT, fused) ----
    const int aA = (tid & 15) * 2, kA = (tid >> 4) * 8;
    float acc2[2][8];
#pragma unroll
    for (int ia = 0; ia < 2; ++ia)
#pragma unroll
        for (int j = 0; j < 8; ++j) acc2[ia][j] = 0.f;
#pragma unroll 4
    for (int n = 0; n < TM; ++n) {
        const float a0v = adjTe[n * 33 + aA], a1v = adjTe[n * 33 + aA + 1];
        ushort4 u0 = *(const ushort4*)&Bt[n * 136 + kA];
        ushort4 u1 = *(const ushort4*)&Bt[n * 136 + kA + 4];
        float sv[8] = {b2f(u0.x), b2f(u0.y), b2f(u0.z), b2f(u0.w),
                       b2f(u1.x), b2f(u1.y), b2f(u1.z), b2f(u1.w)};
#pragma unroll
        for (int j = 0; j < 8; ++j) {
            acc2[0][j] += a0v * sv[j];
            acc2[1][j] += a1v * sv[j];
        }
    }
    float* pdst = part + (size_t)blockIdx.x * (NA * HID);
#pragma unroll
    for (int ia = 0; ia < 2; ++ia) {
        *(float4*)&pdst[(aA + ia) * HID + kA] =
            make_float4(acc2[ia][0], acc2[ia][1], acc2[ia][2], acc2[ia][3]);
        *(float4*)&pdst[(aA + ia) * HID + kA + 4] =
            make_float4(acc2[ia][4], acc2[ia][5], acc2[ia][6], acc2[ia][7]);
    }
}

// T[j] = sum_b part[b][j] (256 blocks x 16 cols). WCS=1: blocks 256..287 also
// reduce csPart columns into colsum (old k_cs_red fused).
template<int WCS>
__global__ __launch_bounds__(256) void k_Tred(const float* __restrict__ part,
                                              float* __restrict__ T,
                                              const float* __restrict__ csPart,
                                              float* __restrict__ colsum) {
    __shared__ float red[256];
    const int tid = threadIdx.x;
    if (WCS && blockIdx.x >= 256) {
        const int a = blockIdx.x - 256;
        float s = 0.f;
        for (int b = tid; b < NBLK; b += 256) s += csPart[a * NBLK + b];
        red[tid] = s;
        __syncthreads();
        for (int st = 128; st > 0; st >>= 1) {
            if (tid < st) red[tid] += red[tid + st];
            __syncthreads();
        }
        if (tid == 0) colsum[a] = red[0];
        return;
    }
    const int jj = tid & 15, bq = tid >> 4;
    const int j = blockIdx.x * 16 + jj;
    float s = 0.f;
#pragma unroll 8
    for (int b = bq; b < NBLK; b += 16) s += part[(size_t)b * (NA * HID) + j];
    red[tid] = s;
    __syncthreads();
    if (bq == 0) {
        float t = 0.f;
#pragma unroll
        for (int q = 0; q < 16; ++q) t += red[q * 16 + jj];
        T[j] = t;
    }
}

// agg[a][n] = sum_j T[a][j] * encW[j][n]  (W^T packed bf16; tiny GEMM)
__global__ __launch_bounds__(128) void k_small(const float* __restrict__ T,
                                               const u16* __restrict__ pw,
                                               const int hop,
                                               float* __restrict__ agg) {
    __shared__ float tr[HID];
    const int a = blockIdx.x, n = threadIdx.x;
    tr[n] = T[a * HID + n];
    __syncthreads();
    const u16* w = pw + PK_ENCWT + hop * HID * HID + n * HID;
    float s = 0.f;
#pragma unroll 4
    for (int j4 = 0; j4 < HID; j4 += 4) {
        ushort4 u = *(const ushort4*)(w + j4);
        s += tr[j4] * b2f(u.x) + tr[j4 + 1] * b2f(u.y) +
             tr[j4 + 2] * b2f(u.z) + tr[j4 + 3] * b2f(u.w);
    }
    agg[a * HID + n] = s;
}

// Fused e2(hop0) + aggT(hop1): xc0 tile computed in-LDS (bf16), never written
// to global; part[b][a][k] = sum_n adjT[n][a]*xc0[n][k]. grid = NBLK, per-tile.
__global__ __launch_bounds__(256) void k_e2a(const float* __restrict__ adj,
                                             const float* __restrict__ rowsum,
                                             const float* __restrict__ colsum,
                                             const float* __restrict__ agg,
                                             const u16* __restrict__ pw,
                                             float* __restrict__ part) {
    __shared__ float aggn[NA][LDA];
    __shared__ float adjT[TM][NA + 1];
    __shared__ __align__(8) u16 xcs[TM * 136];
    __shared__ float csl[NA], rsl[TM];
    const int tid = threadIdx.x;
    const int row0 = blockIdx.x * TM;
    const int n0 = (tid & 31) * 4, m0 = (tid >> 5) * 8;
    const int a0 = (tid & 15) * 2, k0 = (tid >> 4) * 8;

    if (tid < NA) csl[tid] = fmaxf(colsum[tid], EPSS);
    if (tid >= 64 && tid < 128) {
        const int m = tid - 64, g = row0 + m;
        rsl[m] = (g < NN) ? 1.f / fmaxf(rowsum[g], EPSS) : 0.f;
    }
    for (int i = tid; i < TM * NA; i += 256) {
        const int m = i >> 5, a = i & 31, g = row0 + m;
        adjT[m][a] = (g < NN) ? adj[(size_t)g * NA + a] : 0.f;
    }
    __syncthreads();
    for (int i = tid; i < (NA * HID) / 4; i += 256) {
        const int a = i >> 5, k4 = (i & 31) << 2;
        float4 v = *(const float4*)(agg + a * HID + k4);
        const float inv = 1.f / csl[a];
        v.x *= inv; v.y *= inv; v.z *= inv; v.w *= inv;
        *(float4*)&aggn[a][k4] = v;
    }
    float bv[4];
#pragma unroll
    for (int j = 0; j < 4; ++j) bv[j] = b2f(pw[PK_ENCB + n0 + j]);   // hop 0
    __syncthreads();
    // e2 compute: xc0 tile
    float acc[8][4];
#pragma unroll
    for (int i = 0; i < 8; ++i)
#pragma unroll
        for (int j = 0; j < 4; ++j) acc[i][j] = 0.f;
    for (int a = 0; a < NA; ++a) {
        float4 gv = *(const float4*)&aggn[a][n0];
        float gvv[4] = {gv.x, gv.y, gv.z, gv.w};
#pragma unroll
        for (int i = 0; i < 8; ++i) {
            const float av = adjT[m0 + i][a];
#pragma unroll
            for (int j = 0; j < 4; ++j) acc[i][j] += av * gvv[j];
        }
    }
#pragma unroll
    for (int i = 0; i < 8; ++i) {
        const float r = rsl[m0 + i];
        ushort4 o;
        o.x = f2b(fmaxf(r * acc[i][0] + bv[0], 0.f));
        o.y = f2b(fmaxf(r * acc[i][1] + bv[1], 0.f));
        o.z = f2b(fmaxf(r * acc[i][2] + bv[2], 0.f));
        o.w = f2b(fmaxf(r * acc[i][3] + bv[3], 0.f));
        *(ushort4*)&xcs[(m0 + i) * 136 + n0] = o;
    }
    __syncthreads();                         // xcs ready
    // aggT phase: part[b] = adjT^T @ xc0  (invalid rows: adjT=0 -> no contrib)
    float acc2[2][8];
#pragma unroll
    for (int ia = 0; ia < 2; ++ia)
#pragma unroll
        for (int j = 0; j < 8; ++j) acc2[ia][j] = 0.f;
#pragma unroll 4
    for (int n = 0; n < TM; ++n) {
        const float a0v = adjT[n][a0], a1v = adjT[n][a0 + 1];
        ushort4 u0 = *(const ushort4*)&xcs[n * 136 + k0];
        ushort4 u1 = *(const ushort4*)&xcs[n * 136 + k0 + 4];
        float sv[8] = {b2f(u0.x), b2f(u0.y), b2f(u0.z), b2f(u0.w),
                       b2f(u1.x), b2f(u1.y), b2f(u1.z), b2f(u1.w)};
#pragma unroll
        for (int j = 0; j < 8; ++j) {
            acc2[0][j] += a0v * sv[j];
            acc2[1][j] += a1v * sv[j];
        }
    }
    float* dst = part + (size_t)blockIdx.x * (NA * HID);
#pragma unroll
    for (int ia = 0; ia < 2; ++ia) {
        *(float4*)&dst[(a0 + ia) * HID + k0] =
            make_float4(acc2[ia][0], acc2[ia][1], acc2[ia][2], acc2[ia][3]);
        *(float4*)&dst[(a0 + ia) * HID + k0 + 4] =
            make_float4(acc2[ia][4], acc2[ia][5], acc2[ia][6], acc2[ia][7]);
    }
}

// Fused e2(hop1) + final: xc1 computed in registers (fp32, never materialized),
// z = LN(xc1 + h) -> out z; pred = prelu(z@w1+b1)@w2+b2 (MFMA).
__global__ __launch_bounds__(256) void k_e2f(const float* __restrict__ adj,
                                             const float* __restrict__ rowsum,
                                             const float* __restrict__ colsum,
                                             const float* __restrict__ agg,
                                             const u16* __restrict__ pw,
                                             float* __restrict__ out) {
    __shared__ __align__(16) u16 As[64 * 136];       // aggn(A) -> z bf16 -> t1
    __shared__ __align__(16) u16 uniB[128 * 136];    // adjT(A) -> zT fp32 -> Bt
    __shared__ float smu[TM], sinv[TM], sg[HID], sb[HID], w2s[2 * HID];
    __shared__ float csl[NA], rsl[TM];
    float* aggn  = (float*)As;       // [NA][LDA] 16.9KB <= 17.4KB
    float* adjTf = (float*)uniB;     // [TM][NA+1] 8.4KB
    float* zT    = (float*)uniB;     // [64][132] fp32 (phase B)
    const int tid = threadIdx.x;
    const int row0 = blockIdx.x * TM;
    const int lane = tid & 63, wv = tid >> 6, rowBase = wv * 16;
    const int lr = lane & 15, lq = lane >> 4;
    const int n0 = (tid & 31) * 4, m0 = (tid >> 5) * 8;
    const float* h = out + Z_OFF;

    // ---- phase A: e2 hop 1 ----
    if (tid < NA) csl[tid] = fmaxf(colsum[tid], EPSS);
    if (tid >= 64 && tid < 128) {
        const int m = tid - 64, g = row0 + m;
        rsl[m] = (g < NN) ? 1.f / fmaxf(rowsum[g], EPSS) : 0.f;
    }
    for (int i = tid; i < TM * NA; i += 256) {
        const int m = i >> 5, a = i & 31, g = row0 + m;
        adjTf[m * (NA + 1) + a] = (g < NN) ? adj[(size_t)g * NA + a] : 0.f;
    }
    __syncthreads();
    for (int i = tid; i < (NA * HID) / 4; i += 256) {
        const int a = i >> 5, k4 = (i & 31) << 2;
        float4 v = *(const float4*)(agg + a * HID + k4);
        const float inv = 1.f / csl[a];
        v.x *= inv; v.y *= inv; v.z *= inv; v.w *= inv;
        *(float4*)&aggn[a * LDA + k4] = v;
    }
    __syncthreads();
    float acc[8][4];
#pragma unroll
    for (int i = 0; i < 8; ++i)
#pragma unroll
        for (int j = 0; j < 4; ++j) acc[i][j] = 0.f;
    for (int a = 0; a < NA; ++a) {
        float4 gv = *(const float4*)&aggn[a * LDA + n0];
        float gvv[4] = {gv.x, gv.y, gv.z, gv.w};
#pragma unroll
        for (int i = 0; i < 8; ++i) {
            const float av = adjTf[(m0 + i) * (NA + 1) + a];
#pragma unroll
            for (int j = 0; j < 4; ++j) acc[i][j] += av * gvv[j];
        }
    }
    float bv[4];
#pragma unroll
    for (int j = 0; j < 4; ++j) bv[j] = b2f(pw[PK_ENCB + HID + n0 + j]);  // hop 1
    float xcv[8][4];
#pragma unroll
    for (int i = 0; i < 8; ++i) {
        const float r = rsl[m0 + i];
#pragma unroll
        for (int j = 0; j < 4; ++j)
            xcv[i][j] = fmaxf(r * acc[i][j] + bv[j], 0.f);
    }
    __syncthreads();                     // aggn/adjT reads done
    // ---- phase B: zT = xc1 + h ----
#pragma unroll
    for (int i = 0; i < 8; ++i) {
        const int g = row0 + m0 + i;
        float4 hv = make_float4(0.f, 0.f, 0.f, 0.f);
        if (g < NN) hv = *(const float4*)(h + (size_t)g * HID + n0);
        float4 zv = make_float4(xcv[i][0] + hv.x, xcv[i][1] + hv.y,
                                xcv[i][2] + hv.z, xcv[i][3] + hv.w);
        *(float4*)&zT[(m0 + i) * 132 + n0] = zv;
    }
    if (tid < HID) { sg[tid] = b2f(pw[PK_LNG + tid]); sb[tid] = b2f(pw[PK_LNB + tid]); }
    w2s[tid] = b2f(pw[PK_CLSW2 + tid]);
    __syncthreads();
    // ---- LN ----
    if (tid < TM) {
        float s = 0.f;
        for (int k = 0; k < HID; ++k) s += zT[tid * 132 + k];
        const float mu = s * (1.f / HID);
        float v = 0.f;
        for (int k = 0; k < HID; ++k) { const float d = zT[tid * 132 + k] - mu; v += d * d; }
        smu[tid] = mu;
        sinv[tid] = rsqrtf(v * (1.f / HID) + LN_EPS);
    }
    __syncthreads();
    for (int i = tid; i < TM * 32; i += 256) {
        const int m = i >> 5, k4 = (i & 31) << 2, g = row0 + m;
        float4 v = *(const float4*)&zT[m * 132 + k4];
        const float mu = smu[m], inv = sinv[m];
        v.x = (v.x - mu) * inv * sg[k4 + 0] + sb[k4 + 0];
        v.y = (v.y - mu) * inv * sg[k4 + 1] + sb[k4 + 1];
        v.z = (v.z - mu) * inv * sg[k4 + 2] + sb[k4 + 2];
        v.w = (v.w - mu) * inv * sg[k4 + 3] + sb[k4 + 3];
        if (g < NN) *(float4*)&out[Z_OFF + (size_t)g * HID + k4] = v;
        ushort4 o; o.x = f2b(v.x); o.y = f2b(v.y); o.z = f2b(v.z); o.w = f2b(v.w);
        *(ushort4*)&As[m * 136 + k4] = o;
    }
    __syncthreads();
    for (int i = tid; i < 128 * 32; i += 256) {
        const int n = i >> 5, k4 = (i & 31) << 2;
        *(ushort4*)&uniB[n * 136 + k4] =
            *(const ushort4*)(pw + PK_CLSW1T + n * 128 + k4);
    }
    __syncthreads();
    f32x4 macc[8];
    const f32x4 z4 = {0.f, 0.f, 0.f, 0.f};
#pragma unroll
    for (int t = 0; t < 8; ++t) macc[t] = z4;
    mfma_64x128(As, uniB, macc, lane, rowBase);
    __syncthreads();
#pragma unroll
    for (int t = 0; t < 8; ++t) {
        const int col = t * 16 + lr;
        const float bc = b2f(pw[PK_CLSB1 + col]);
        const float pa = b2f(pw[PK_PRELU + col]);
#pragma unroll
        for (int r = 0; r < 4; ++r) {
            float v = macc[t][r] + bc;
            v = v > 0.f ? v : pa * v;
            As[(rowBase + lq * 4 + r) * 136 + col] = f2b(v);
        }
    }
    __syncthreads();
    if (tid < 128) {
        const int r = tid >> 1, c = tid & 1, g = row0 + r;
        if (g < NN) {
            float s = b2f(pw[PK_CLSB2 + c]);
            for (int k = 0; k < HID; ++k) s += b2f(As[r * 136 + k]) * w2s[k * 2 + c];
            out[PRED_OFF + (size_t)g * 2 + c] = s;
        }
    }
}

extern "C" void kernel_launch(void* const* d_in, const int* in_sizes, int n_in,
                              void* d_out, int out_size, void* d_ws, size_t ws_size,
                              hipStream_t stream) {
    const bool ok = (n_in >= 19) && (out_size == OUT_TOT) &&
                    (ws_size >= WS_NEED_BYTES) &&
                    (in_sizes[0] == NN * FEAT) && (in_sizes[6] == NP * 2 * HID * HID) &&
                    (in_sizes[10] == 2 * HID * HID) && (in_sizes[17] == HID * 2);
    if (!ok) {
        hipMemsetAsync(d_out, 0, (size_t)OUT_TOT * 4, stream);
        return;
    }

    float* ws    = (float*)d_ws;
    u16*   wsu   = (u16*)d_ws;
    float* out   = (float*)d_out;
    int*   flags = (int*)(ws + FLAG_F);
    float* hbuf  = out + Z_OFF;       // h (fp32) parked in z output region
    u16*   pw    = wsu + PW_U;
    float* xcf   = (float*)(wsu + XC_U);   // dead XC+SUP regions (25.6 MB)
    float* csPart = xcf;                   // 100 KB
    float* partb = xcf + 32768;            // NBLK*4096 floats (12.81 MB)
    float* Tbuf  = ws + HB_F;              // T (4096 floats); hb dead post-attn
    float* wcv   = ws + AGG1_F;            // wc[p][a]: dead until hop-1 small

    P19 pa;
    for (int i = 0; i < 19; ++i) pa.q[i] = d_in[i];
    k_detect_all<<<19, 256, 0, stream>>>(pa, flags);
    k_convT<<<161, 256, 0, stream>>>(pa, flags, pw);   // tiles + vector params

    k_pre<<<NP * NA, 128, 0, stream>>>(d_in[5], d_in[6], d_in[7], d_in[8],
                                       ws + HB_F, wcv, flags);
    k_anchor<<<NA / 2, 256, 0, stream>>>(d_in[5], d_in[14], d_in[15], d_in[16],
                                         d_in[17], d_in[18], out, flags);

    // h = relu(x@W1+b1)@W2+b2 fused; x A-frags in regs, Bt64 halves, 4 blk/CU
    k_gemm2<<<NBLK, 256, 0, stream>>>(d_in[0], pw, hbuf, flags);

    // fused attention + rowsum + colsum partials + hop-0 aggT partials
    k_fattn<<<NBLK, 256, 0, stream>>>(hbuf, pw, ws + HB_F, wcv, ws + ADJ_F,
                                      ws + RS_F, csPart, partb);

    // hop 0: T0-reduce (+colsum fused) ; agg0 = (T0/cs) @ encW0
    k_Tred<1><<<288, 256, 0, stream>>>(partb, Tbuf, csPart, ws + CS_F);
    k_small<<<NA, 128, 0, stream>>>(Tbuf, pw, 0, ws + AGG0_F);
    // fused: xc0 (in-LDS only) + T1 partials
    k_e2a<<<NBLK, 256, 0, stream>>>(ws + ADJ_F, ws + RS_F, ws + CS_F, ws + AGG0_F,
                                    pw, partb);
    k_Tred<0><<<256, 256, 0, stream>>>(partb, Tbuf, csPart, ws + CS_F);
    k_small<<<NA, 128, 0, stream>>>(Tbuf, pw, 1, ws + AGG1_F);
    // fused: xc1 (in-regs only) + LN + classifier
    k_e2f<<<NBLK, 256, 0, stream>>>(ws + ADJ_F, ws + RS_F, ws + CS_F, ws + AGG1_F,
                                    pw, out);
}